// Round 8
// baseline (113.993 us; speedup 1.0000x reference)
//
#include <hip/hip_runtime.h>

#define B_ 8
#define N_ 2048
#define D_ 131
#define COSTR 133     // attn merge row stride (float), odd
#define SXSTR 164     // proj sX row stride (float), 656B = 16B-aligned
#define CSTR 168      // proj sC row stride (ushort), 336B = 16B-aligned
#define TSTR 72       // proj sT row stride (ushort), 144B = 16B-aligned

typedef __attribute__((ext_vector_type(8))) short s16x8;
typedef __attribute__((ext_vector_type(16))) float f32x16;

__device__ __forceinline__ ushort f2bf(float x) {
  uint u = __float_as_uint(x);
  u += 0x7fffu + ((u >> 16) & 1u);
  return (ushort)(u >> 16);
}
__device__ __forceinline__ float bf2f(ushort h) {
  return __uint_as_float(((uint)h) << 16);
}
__device__ __forceinline__ uint bfpair(float a, float b) {
  uint ua = __float_as_uint(a);
  ua += 0x7fffu + ((ua >> 16) & 1u);
  uint ub = __float_as_uint(b);
  ub += 0x7fffu + ((ub >> 16) & 1u);
  return (ua >> 16) | (ub & 0xffff0000u);
}

// ---- 32x32 fragment layouts (all hot-loop loads 16B/lane, wave-contiguous) --
// Rf (Q/K): [nt=token/32][ch16(9)][lane][8]
//   value = X[32*nt + (l&31)][16*ch + 8*(l>>5) + j]
// Vf:       [kt=key/32][t2(2)][dt32(5)][lane][8]
//   value = V[32*kt + 16*t2 + 8*(l>>5) + j][32*dt + (l&31)]
// Wf:       [p][hi/lo][et32(5)][ch16(9)][lane][8]
__device__ __forceinline__ size_t rf32_idx(int nt, int ch, int l) {
  return ((size_t)(nt * 9 + ch) * 64 + l) * 8;
}
__device__ __forceinline__ size_t vf32_idx(int kt, int t2, int dt, int l) {
  return ((size_t)(((kt * 2) + t2) * 5 + dt) * 64 + l) * 8;
}
__device__ __forceinline__ size_t wf32_idx(int p, int h, int et, int ch, int l) {
  return ((size_t)((((p * 2 + h) * 5 + et) * 9) + ch) * 64 + l) * 8;
}

// ---------------------------------------------------------------------------
// Kernel 0: W -> hi/lo bf16 32x32-fragments. grid(3), block(256).
// ---------------------------------------------------------------------------
__global__ void cast_w_kernel(const float* __restrict__ Wq,
                              const float* __restrict__ Wk,
                              const float* __restrict__ Wv,
                              ushort* __restrict__ Whl) {
  const int p = blockIdx.x;
  const float* __restrict__ W = (p == 0) ? Wq : (p == 1) ? Wk : Wv;
  for (int i = threadIdx.x; i < 5 * 9 * 64; i += blockDim.x) {
    const int et = i / 576;
    const int rem = i - et * 576;
    const int ch = rem >> 6;
    const int l = rem & 63;
    const int e = et * 32 + (l & 31);
    s16x8 hi, lo;
#pragma unroll
    for (int j = 0; j < 8; ++j) {
      const int d = ch * 16 + (l >> 5) * 8 + j;
      const float val = (e < D_ && d < D_) ? W[e * D_ + d] : 0.f;
      const ushort h = f2bf(val);
      hi[j] = (short)h;
      lo[j] = (short)f2bf(val - bf2f(h));
    }
    *(s16x8*)(Whl + wf32_idx(p, 0, et, ch, l)) = hi;
    *(s16x8*)(Whl + wf32_idx(p, 1, et, ch, l)) = lo;
  }
}

// ---- proj per-wave compute, templated so all array indexing is static ------
template <int ET0, int NET>
__device__ __forceinline__ void compute_acc(const float* sX,
                                            const ushort* __restrict__ Whl,
                                            int p, int tg, int l,
                                            f32x16 acc[3]) {
  const int l31 = l & 31, hi = l >> 5;
#pragma unroll
  for (int ch = 0; ch < 9; ++ch) {
    const float* xp = sX + (size_t)(32 * tg + l31) * SXSTR + ch * 16 + hi * 8;
    const float4 x0 = *(const float4*)xp;
    const float4 x1 = *(const float4*)(xp + 4);
    const float xv[8] = {x0.x, x0.y, x0.z, x0.w, x1.x, x1.y, x1.z, x1.w};
    s16x8 ah, al;
#pragma unroll
    for (int j = 0; j < 8; ++j) {
      const ushort h = f2bf(xv[j]);
      ah[j] = (short)h;
      al[j] = (short)f2bf(xv[j] - bf2f(h));
    }
    s16x8 bh[NET], bl[NET];
#pragma unroll
    for (int u = 0; u < NET; ++u) {
      bh[u] = *(const s16x8*)(Whl + wf32_idx(p, 0, ET0 + u, ch, l));
      bl[u] = *(const s16x8*)(Whl + wf32_idx(p, 1, ET0 + u, ch, l));
    }
#pragma unroll
    for (int u = 0; u < NET; ++u) {
      acc[u] = __builtin_amdgcn_mfma_f32_32x32x16_bf16(ah, bh[u], acc[u], 0, 0, 0);
      acc[u] = __builtin_amdgcn_mfma_f32_32x32x16_bf16(al, bh[u], acc[u], 0, 0, 0);
      acc[u] = __builtin_amdgcn_mfma_f32_32x32x16_bf16(ah, bl[u], acc[u], 0, 0, 0);
    }
  }
}

template <int ET0, int NET>
__device__ __forceinline__ void epiQK(const f32x16 acc[3], ushort* sC,
                                      const float* sB, int tg, int l,
                                      bool scale) {
  const int l31 = l & 31, hi = l >> 5;
  const float ISC = 0.08737040566610379f;
#pragma unroll
  for (int u = 0; u < NET; ++u) {
    const int e = 32 * (ET0 + u) + l31;
    const float bval = sB[e];
#pragma unroll
    for (int r = 0; r < 16; ++r) {
      const int tok = 32 * tg + (r & 3) + 8 * (r >> 2) + 4 * hi;
      float val = acc[u][r] + bval;
      if (scale) val *= ISC;
      sC[(size_t)tok * CSTR + e] = f2bf(val);
    }
  }
}

template <int ET0, int NET>
__device__ __forceinline__ void epiV(const f32x16 acc[3], ushort* sT,
                                     const float* sB, int tg, int l) {
  const int l31 = l & 31, hi = l >> 5;
#pragma unroll
  for (int u = 0; u < NET; ++u) {
    const int e = 32 * (ET0 + u) + l31;
    if (e < D_) {
      const float bval = sB[e];
#pragma unroll
      for (int g = 0; g < 4; ++g) {
        const float v0 = acc[u][4 * g + 0] + bval;
        const float v1 = acc[u][4 * g + 1] + bval;
        const float v2 = acc[u][4 * g + 2] + bval;
        const float v3 = acc[u][4 * g + 3] + bval;
        uint2 pk;
        pk.x = bfpair(v0, v1);
        pk.y = bfpair(v2, v3);
        *(uint2*)(sT + (size_t)e * TSTR + 32 * tg + 8 * g + 4 * hi) = pk;
      }
    }
  }
}

// ---------------------------------------------------------------------------
// Kernel 1: MFMA projections (32x32, 3-pass hi/lo). grid(256,3), block 256 =
// 4 waves: wave = (tg = token-group of 32, eh = et-half {0,1,2}/{3,4}).
// ---------------------------------------------------------------------------
__global__ __launch_bounds__(256, 3) void proj_gemm(
    const float* __restrict__ q, const float* __restrict__ k,
    const float* __restrict__ v, const float* __restrict__ bq,
    const float* __restrict__ bk, const float* __restrict__ bv,
    const ushort* __restrict__ Whl, ushort* __restrict__ Qf,
    ushort* __restrict__ Kf, ushort* __restrict__ Vf) {
  const int p = blockIdx.y;
  const float* __restrict__ x = (p == 0) ? q : (p == 1) ? k : v;
  const float* __restrict__ bias = (p == 0) ? bq : (p == 1) ? bk : bv;

  __shared__ __align__(16) char smem[64 * SXSTR * 4];  // 41984 B (union)
  float* sX = (float*)smem;
  ushort* sC = (ushort*)smem;  // [64][CSTR]
  ushort* sT = (ushort*)smem;  // [160][TSTR]
  __shared__ float sB[160];

  const int tid = threadIdx.x;
  const int r0 = blockIdx.x * 64;

  {
    const float* __restrict__ xbase = x + (size_t)r0 * D_;
    for (int i = tid; i < 64 * D_ / 4; i += 256) {
      const float4 v4 = *(const float4*)(xbase + i * 4);
      const float vv[4] = {v4.x, v4.y, v4.z, v4.w};
#pragma unroll
      for (int j = 0; j < 4; ++j) {
        const int nl = i * 4 + j;
        const int r = nl / D_;
        const int d = nl - r * D_;
        sX[r * SXSTR + d] = vv[j];
      }
    }
    for (int i = tid; i < 64 * 33; i += 256) {
      const int r = i / 33;
      sX[r * SXSTR + D_ + (i - r * 33)] = 0.f;
    }
  }
  if (tid < 160) sB[tid] = (tid < D_) ? bias[tid] : 0.f;
  __syncthreads();

  const int w = tid >> 6;
  const int l = tid & 63;
  const int tg = w & 1;
  const int eh = w >> 1;

  f32x16 acc[3];
  acc[0] = f32x16{};
  acc[1] = f32x16{};
  acc[2] = f32x16{};
  if (eh == 0)
    compute_acc<0, 3>(sX, Whl, p, tg, l, acc);
  else
    compute_acc<3, 2>(sX, Whl, p, tg, l, acc);

  __syncthreads();  // done with sX

  if (p < 2) {
    if (eh == 0)
      epiQK<0, 3>(acc, sC, sB, tg, l, p == 0);
    else
      epiQK<3, 2>(acc, sC, sB, tg, l, p == 0);
    __syncthreads();
    ushort* __restrict__ dst = (p == 0) ? Qf : Kf;
    const int nt0 = r0 >> 5;
    for (int i = tid; i < 2 * 9 * 64; i += 256) {
      const int ntl = i / 576;
      const int rem = i - ntl * 576;
      const int ch = rem >> 6;
      const int l2 = rem & 63;
      const s16x8 fr = *(const s16x8*)(sC + (size_t)(32 * ntl + (l2 & 31)) * CSTR +
                                       ch * 16 + (l2 >> 5) * 8);
      *(s16x8*)(dst + rf32_idx(nt0 + ntl, ch, l2)) = fr;
    }
  } else {
    // pad rows 131..159: ones at 131 (l-fusion), zeros above
    for (int i = tid; i < 29 * 64; i += 256) {
      const int e = D_ + (i >> 6);
      sT[(size_t)e * TSTR + (i & 63)] = (e == D_) ? (ushort)0x3F80 : (ushort)0;
    }
    if (eh == 0)
      epiV<0, 3>(acc, sT, sB, tg, l);
    else
      epiV<3, 2>(acc, sT, sB, tg, l);
    __syncthreads();
    const int kt0 = r0 >> 5;
    for (int i = tid; i < 2 * 2 * 5 * 64; i += 256) {
      const int ktl = i / 640;
      const int rem = i - ktl * 640;
      const int t2 = rem / 320;
      const int rem2 = rem - t2 * 320;
      const int dt = rem2 >> 6;
      const int l2 = rem2 & 63;
      const s16x8 fr = *(const s16x8*)(sT + (size_t)(32 * dt + (l2 & 31)) * TSTR +
                                       32 * ktl + 16 * t2 + 8 * (l2 >> 5));
      *(s16x8*)(Vf + vf32_idx(kt0 + ktl, t2, dt, l2)) = fr;
    }
  }
}

// ---------------------------------------------------------------------------
// Kernel 2: MFMA flash attention, 32x32, 64 queries/wave (2 q-groups).
// grid(256): b=id&7 (XCD-pin), q0=(id>>3)*64. block 256 = 4 waves, ALL
// sharing the same 64 queries (Q frags in LDS); wave w owns keys
// [512w,512w+512) as 16 tiles of 32. K/V loads serve BOTH q-groups (2x the
// MFMA:VMEM ratio of R7 -> halves L2 traffic). 1 wave/SIMD by design:
// ILP from 2 independent QK chains + 10 PV chains. K reg-dbuf; V prefetch
// at tile start; l fused via Vt ones-row (d=131); defer-max.
// Merge: 2 chunks of 32 q, symmetric across waves.
// ---------------------------------------------------------------------------
__global__ __launch_bounds__(256, 1) void attn_mfma(
    const ushort* __restrict__ Qf, const ushort* __restrict__ Kf,
    const ushort* __restrict__ Vf, float* __restrict__ out) {
  const int id = blockIdx.x;
  const int b = id & 7;
  const int qg2 = id >> 3;        // 0..31, q0 = qg2*64
  const int tid = threadIdx.x;
  const int w = tid >> 6;
  const int l = tid & 63;
  const int l31 = l & 31;
  const int hi = l >> 5;

  __shared__ ushort sQ[2 * 9 * 64 * 8];  // 18432 B: 2 q-groups of frags
  __shared__ float cO[4][32][COSTR];     // 68096 B
  __shared__ float cm[4][32];            // 512 B

  // stage Q fragments: 2 consecutive nt blocks, contiguous in Qf
  {
    const uint4* src = (const uint4*)(Qf + rf32_idx(b * 64 + qg2 * 2, 0, 0));
    uint4* dq = (uint4*)sQ;
    for (int i = tid; i < 1152; i += 256) dq[i] = src[i];
  }
  // preload first K tile
  s16x8 kA[9], kB[9];
  const int ktbase = b * 64 + w * 16;
#pragma unroll
  for (int ch = 0; ch < 9; ++ch)
    kA[ch] = *(const s16x8*)(Kf + rf32_idx(ktbase, ch, l));
  __syncthreads();

  f32x16 o0[5], o1[5];
#pragma unroll
  for (int dt = 0; dt < 5; ++dt) {
    o0[dt] = f32x16{};
    o1[dt] = f32x16{};
  }
  float mreg0 = -1e30f, mreg1 = -1e30f;

  auto tile_body = [&](s16x8(&KC)[9], s16x8(&KN)[9], int ktg, int ktgn) {
    // V fragments (shared by both q-groups)
    s16x8 vf[2][5];
#pragma unroll
    for (int t2 = 0; t2 < 2; ++t2)
#pragma unroll
      for (int dt = 0; dt < 5; ++dt)
        vf[t2][dt] = *(const s16x8*)(Vf + vf32_idx(ktg, t2, dt, l));
    // prefetch next K tile
#pragma unroll
    for (int ch = 0; ch < 9; ++ch)
      KN[ch] = *(const s16x8*)(Kf + rf32_idx(ktgn, ch, l));
    // QK for both q-groups: two independent MFMA chains
    f32x16 s0 = f32x16{}, s1 = f32x16{};
#pragma unroll
    for (int ch = 0; ch < 9; ++ch) {
      const s16x8 qc0 = *(const s16x8*)(sQ + (ch * 64 + l) * 8);
      const s16x8 qc1 = *(const s16x8*)(sQ + ((9 + ch) * 64 + l) * 8);
      s0 = __builtin_amdgcn_mfma_f32_32x32x16_bf16(KC[ch], qc0, s0, 0, 0, 0);
      s1 = __builtin_amdgcn_mfma_f32_32x32x16_bf16(KC[ch], qc1, s1, 0, 0, 0);
    }
    // softmax + PV per q-group
    auto softmax_pv = [&](f32x16& s, float& mreg, f32x16(&og)[5]) {
      float tm = s[0];
#pragma unroll
      for (int r = 1; r < 16; ++r) tm = fmaxf(tm, s[r]);
      tm = fmaxf(tm, __shfl_xor(tm, 32, 64));
      if (__any(tm > mreg)) {
        const float mo = mreg;
        const float mn = fmaxf(mo, tm);
        mreg = mn;
        const float f = __expf(mo - mn);
        float fr[16];
#pragma unroll
        for (int r = 0; r < 16; ++r)
          fr[r] = __shfl(f, (r & 3) + 8 * (r >> 2) + 4 * hi, 64);
#pragma unroll
        for (int dt = 0; dt < 5; ++dt)
#pragma unroll
          for (int r = 0; r < 16; ++r) og[dt][r] *= fr[r];
      }
      float pp[16];
#pragma unroll
      for (int r = 0; r < 16; ++r) pp[r] = __expf(s[r] - mreg);
      uint pk0[4], pk1[4];
#pragma unroll
      for (int wd = 0; wd < 4; ++wd) {
        pk0[wd] = bfpair(pp[2 * wd], pp[2 * wd + 1]);
        pk1[wd] = bfpair(pp[8 + 2 * wd], pp[8 + 2 * wd + 1]);
      }
      s16x8 pa[2];
      {
        const uint x0 = __shfl_xor(hi ? pk0[0] : pk0[2], 32, 64);
        const uint x1 = __shfl_xor(hi ? pk0[1] : pk0[3], 32, 64);
        uint4 u;
        u.x = hi ? x0 : pk0[0];
        u.y = hi ? x1 : pk0[1];
        u.z = hi ? pk0[2] : x0;
        u.w = hi ? pk0[3] : x1;
        pa[0] = *(s16x8*)&u;
      }
      {
        const uint x0 = __shfl_xor(hi ? pk1[0] : pk1[2], 32, 64);
        const uint x1 = __shfl_xor(hi ? pk1[1] : pk1[3], 32, 64);
        uint4 u;
        u.x = hi ? x0 : pk1[0];
        u.y = hi ? x1 : pk1[1];
        u.z = hi ? pk1[2] : x0;
        u.w = hi ? pk1[3] : x1;
        pa[1] = *(s16x8*)&u;
      }
#pragma unroll
      for (int t2 = 0; t2 < 2; ++t2)
#pragma unroll
        for (int dt = 0; dt < 5; ++dt)
          og[dt] = __builtin_amdgcn_mfma_f32_32x32x16_bf16(pa[t2], vf[t2][dt],
                                                           og[dt], 0, 0, 0);
    };
    softmax_pv(s0, mreg0, o0);
    softmax_pv(s1, mreg1, o1);
  };

  for (int i = 0; i < 8; ++i) {
    const int kt = ktbase + 2 * i;
    tile_body(kA, kB, kt, kt + 1);
    tile_body(kB, kA, kt + 1, (i < 7) ? kt + 2 : kt + 1);
  }

  // ---- 2-chunk symmetric merge (chunk c = q-group c) ----
#pragma unroll
  for (int c = 0; c < 2; ++c) {
    if (c) __syncthreads();  // previous chunk's merge reads done
    if (l < 32) cm[w][l] = c ? mreg1 : mreg0;
#pragma unroll
    for (int dt = 0; dt < 5; ++dt) {
      const int d = 32 * dt + l31;
      if (d <= D_) {
#pragma unroll
        for (int r = 0; r < 16; ++r) {
          const int row = (r & 3) + 8 * (r >> 2) + 4 * hi;
          cO[w][row][d] = c ? o1[dt][r] : o0[dt][r];
        }
      }
    }
    __syncthreads();
    for (int rr = 0; rr < 8; ++rr) {
      const int row = w * 8 + rr;
      const float m0 = cm[0][row], m1 = cm[1][row];
      const float m2 = cm[2][row], m3 = cm[3][row];
      const float M = fmaxf(fmaxf(m0, m1), fmaxf(m2, m3));
      const float e0 = __expf(m0 - M);
      const float e1 = __expf(m1 - M);
      const float e2 = __expf(m2 - M);
      const float e3 = __expf(m3 - M);
      const float lsum = cO[0][row][D_] * e0 + cO[1][row][D_] * e1 +
                         cO[2][row][D_] * e2 + cO[3][row][D_] * e3;
      const float inv = 1.f / lsum;
      float* orow = out + ((size_t)b * N_ + qg2 * 64 + c * 32 + row) * D_;
      for (int d = l; d < D_; d += 64) {
        const float val = cO[0][row][d] * e0 + cO[1][row][d] * e1 +
                          cO[2][row][d] * e2 + cO[3][row][d] * e3;
        orow[d] = val * inv;
      }
    }
  }
}

extern "C" void kernel_launch(void* const* d_in, const int* in_sizes, int n_in,
                              void* d_out, int out_size, void* d_ws,
                              size_t ws_size, hipStream_t stream) {
  const float* q = (const float*)d_in[0];
  const float* k = (const float*)d_in[1];
  const float* v = (const float*)d_in[2];
  const float* Wq = (const float*)d_in[3];
  const float* bq = (const float*)d_in[4];
  const float* Wk = (const float*)d_in[5];
  const float* bk = (const float*)d_in[6];
  const float* Wv = (const float*)d_in[7];
  const float* bv = (const float*)d_in[8];
  float* out = (float*)d_out;

  // ws layout (bytes):
  //   Qf  [512 nt][9][64][8]u16   @ 0           (4,718,592)
  //   Kf  same                    @ 4,718,592   (4,718,592)
  //   Vf  [512 kt][2][5][64][8]   @ 9,437,184   (5,242,880)
  //   Whl [3][2][5][9][64][8]u16  @ 14,680,064  (552,960)
  char* wsb = (char*)d_ws;
  ushort* Qf = (ushort*)(wsb);
  ushort* Kf = (ushort*)(wsb + 4718592);
  ushort* Vf = (ushort*)(wsb + 9437184);
  ushort* Whl = (ushort*)(wsb + 14680064);

  hipLaunchKernelGGL(cast_w_kernel, dim3(3), dim3(256), 0, stream, Wq, Wk, Wv,
                     Whl);
  hipLaunchKernelGGL(proj_gemm, dim3(256, 3), dim3(256), 0, stream, q, k, v,
                     bq, bk, bv, Whl, Qf, Kf, Vf);
  hipLaunchKernelGGL(attn_mfma, dim3(256), dim3(256), 0, stream, Qf, Kf, Vf,
                     out);
}

// Round 9
// 68.279 us; speedup vs baseline: 1.6695x; 1.6695x over previous
//
#include <hip/hip_runtime.h>

#define B_ 8
#define N_ 2048
#define D_ 131
#define COSTR 133     // attn merge row stride (float), odd
#define SXSTR 164     // proj sX row stride (float), 656B = 16B-aligned
#define CSTR 168      // proj sC row stride (ushort), 336B = 16B-aligned
#define TSTR 72       // proj sT row stride (ushort), 144B = 16B-aligned

typedef __attribute__((ext_vector_type(8))) short s16x8;
typedef __attribute__((ext_vector_type(16))) float f32x16;

__device__ __forceinline__ ushort f2bf(float x) {
  uint u = __float_as_uint(x);
  u += 0x7fffu + ((u >> 16) & 1u);
  return (ushort)(u >> 16);
}
__device__ __forceinline__ float bf2f(ushort h) {
  return __uint_as_float(((uint)h) << 16);
}
__device__ __forceinline__ uint bfpair(float a, float b) {
  uint ua = __float_as_uint(a);
  ua += 0x7fffu + ((ua >> 16) & 1u);
  uint ub = __float_as_uint(b);
  ub += 0x7fffu + ((ub >> 16) & 1u);
  return (ua >> 16) | (ub & 0xffff0000u);
}

// ---- 32x32 fragment layouts (all hot-loop loads 16B/lane, wave-contiguous) --
// Rf (Q/K): [nt=token/32][ch16(9)][lane][8]
//   value = X[32*nt + (l&31)][16*ch + 8*(l>>5) + j]
// Vf:       [kt=key/32][t2(2)][dt32(5)][lane][8]
//   value = V[32*kt + 16*t2 + 8*(l>>5) + j][32*dt + (l&31)]
// Wf:       [p][hi/lo][et32(5)][ch16(9)][lane][8]
__device__ __forceinline__ size_t rf32_idx(int nt, int ch, int l) {
  return ((size_t)(nt * 9 + ch) * 64 + l) * 8;
}
__device__ __forceinline__ size_t vf32_idx(int kt, int t2, int dt, int l) {
  return ((size_t)(((kt * 2) + t2) * 5 + dt) * 64 + l) * 8;
}
__device__ __forceinline__ size_t wf32_idx(int p, int h, int et, int ch, int l) {
  return ((size_t)((((p * 2 + h) * 5 + et) * 9) + ch) * 64 + l) * 8;
}

// ---------------------------------------------------------------------------
// Kernel 0: W -> hi/lo bf16 32x32-fragments. grid(3), block(256).
// ---------------------------------------------------------------------------
__global__ void cast_w_kernel(const float* __restrict__ Wq,
                              const float* __restrict__ Wk,
                              const float* __restrict__ Wv,
                              ushort* __restrict__ Whl) {
  const int p = blockIdx.x;
  const float* __restrict__ W = (p == 0) ? Wq : (p == 1) ? Wk : Wv;
  for (int i = threadIdx.x; i < 5 * 9 * 64; i += blockDim.x) {
    const int et = i / 576;
    const int rem = i - et * 576;
    const int ch = rem >> 6;
    const int l = rem & 63;
    const int e = et * 32 + (l & 31);
    s16x8 hi, lo;
#pragma unroll
    for (int j = 0; j < 8; ++j) {
      const int d = ch * 16 + (l >> 5) * 8 + j;
      const float val = (e < D_ && d < D_) ? W[e * D_ + d] : 0.f;
      const ushort h = f2bf(val);
      hi[j] = (short)h;
      lo[j] = (short)f2bf(val - bf2f(h));
    }
    *(s16x8*)(Whl + wf32_idx(p, 0, et, ch, l)) = hi;
    *(s16x8*)(Whl + wf32_idx(p, 1, et, ch, l)) = lo;
  }
}

// ---- proj per-wave compute, templated so all array indexing is static ------
template <int ET0, int NET>
__device__ __forceinline__ void compute_acc(const float* sX,
                                            const ushort* __restrict__ Whl,
                                            int p, int tg, int l,
                                            f32x16 acc[3]) {
  const int l31 = l & 31, hi = l >> 5;
#pragma unroll
  for (int ch = 0; ch < 9; ++ch) {
    const float* xp = sX + (size_t)(32 * tg + l31) * SXSTR + ch * 16 + hi * 8;
    const float4 x0 = *(const float4*)xp;
    const float4 x1 = *(const float4*)(xp + 4);
    const float xv[8] = {x0.x, x0.y, x0.z, x0.w, x1.x, x1.y, x1.z, x1.w};
    s16x8 ah, al;
#pragma unroll
    for (int j = 0; j < 8; ++j) {
      const ushort h = f2bf(xv[j]);
      ah[j] = (short)h;
      al[j] = (short)f2bf(xv[j] - bf2f(h));
    }
    s16x8 bh[NET], bl[NET];
#pragma unroll
    for (int u = 0; u < NET; ++u) {
      bh[u] = *(const s16x8*)(Whl + wf32_idx(p, 0, ET0 + u, ch, l));
      bl[u] = *(const s16x8*)(Whl + wf32_idx(p, 1, ET0 + u, ch, l));
    }
#pragma unroll
    for (int u = 0; u < NET; ++u) {
      acc[u] = __builtin_amdgcn_mfma_f32_32x32x16_bf16(ah, bh[u], acc[u], 0, 0, 0);
      acc[u] = __builtin_amdgcn_mfma_f32_32x32x16_bf16(al, bh[u], acc[u], 0, 0, 0);
      acc[u] = __builtin_amdgcn_mfma_f32_32x32x16_bf16(ah, bl[u], acc[u], 0, 0, 0);
    }
  }
}

template <int ET0, int NET>
__device__ __forceinline__ void epiQK(const f32x16 acc[3], ushort* sC,
                                      const float* sB, int tg, int l,
                                      bool scale) {
  const int l31 = l & 31, hi = l >> 5;
  const float ISC = 0.08737040566610379f;
#pragma unroll
  for (int u = 0; u < NET; ++u) {
    const int e = 32 * (ET0 + u) + l31;
    const float bval = sB[e];
#pragma unroll
    for (int r = 0; r < 16; ++r) {
      const int tok = 32 * tg + (r & 3) + 8 * (r >> 2) + 4 * hi;
      float val = acc[u][r] + bval;
      if (scale) val *= ISC;
      sC[(size_t)tok * CSTR + e] = f2bf(val);
    }
  }
}

template <int ET0, int NET>
__device__ __forceinline__ void epiV(const f32x16 acc[3], ushort* sT,
                                     const float* sB, int tg, int l) {
  const int l31 = l & 31, hi = l >> 5;
#pragma unroll
  for (int u = 0; u < NET; ++u) {
    const int e = 32 * (ET0 + u) + l31;
    if (e < D_) {
      const float bval = sB[e];
#pragma unroll
      for (int g = 0; g < 4; ++g) {
        const float v0 = acc[u][4 * g + 0] + bval;
        const float v1 = acc[u][4 * g + 1] + bval;
        const float v2 = acc[u][4 * g + 2] + bval;
        const float v3 = acc[u][4 * g + 3] + bval;
        uint2 pk;
        pk.x = bfpair(v0, v1);
        pk.y = bfpair(v2, v3);
        *(uint2*)(sT + (size_t)e * TSTR + 32 * tg + 8 * g + 4 * hi) = pk;
      }
    }
  }
}

// ---------------------------------------------------------------------------
// Kernel 1: MFMA projections (32x32, 3-pass hi/lo). grid(256,3), block 256 =
// 4 waves: wave = (tg = token-group of 32, eh = et-half {0,1,2}/{3,4}).
// ---------------------------------------------------------------------------
__global__ __launch_bounds__(256, 3) void proj_gemm(
    const float* __restrict__ q, const float* __restrict__ k,
    const float* __restrict__ v, const float* __restrict__ bq,
    const float* __restrict__ bk, const float* __restrict__ bv,
    const ushort* __restrict__ Whl, ushort* __restrict__ Qf,
    ushort* __restrict__ Kf, ushort* __restrict__ Vf) {
  const int p = blockIdx.y;
  const float* __restrict__ x = (p == 0) ? q : (p == 1) ? k : v;
  const float* __restrict__ bias = (p == 0) ? bq : (p == 1) ? bk : bv;

  __shared__ __align__(16) char smem[64 * SXSTR * 4];  // 41984 B (union)
  float* sX = (float*)smem;
  ushort* sC = (ushort*)smem;  // [64][CSTR]
  ushort* sT = (ushort*)smem;  // [160][TSTR]
  __shared__ float sB[160];

  const int tid = threadIdx.x;
  const int r0 = blockIdx.x * 64;

  {
    const float* __restrict__ xbase = x + (size_t)r0 * D_;
    for (int i = tid; i < 64 * D_ / 4; i += 256) {
      const float4 v4 = *(const float4*)(xbase + i * 4);
      const float vv[4] = {v4.x, v4.y, v4.z, v4.w};
#pragma unroll
      for (int j = 0; j < 4; ++j) {
        const int nl = i * 4 + j;
        const int r = nl / D_;
        const int d = nl - r * D_;
        sX[r * SXSTR + d] = vv[j];
      }
    }
    for (int i = tid; i < 64 * 33; i += 256) {
      const int r = i / 33;
      sX[r * SXSTR + D_ + (i - r * 33)] = 0.f;
    }
  }
  if (tid < 160) sB[tid] = (tid < D_) ? bias[tid] : 0.f;
  __syncthreads();

  const int w = tid >> 6;
  const int l = tid & 63;
  const int tg = w & 1;
  const int eh = w >> 1;

  f32x16 acc[3];
  acc[0] = f32x16{};
  acc[1] = f32x16{};
  acc[2] = f32x16{};
  if (eh == 0)
    compute_acc<0, 3>(sX, Whl, p, tg, l, acc);
  else
    compute_acc<3, 2>(sX, Whl, p, tg, l, acc);

  __syncthreads();  // done with sX

  if (p < 2) {
    if (eh == 0)
      epiQK<0, 3>(acc, sC, sB, tg, l, p == 0);
    else
      epiQK<3, 2>(acc, sC, sB, tg, l, p == 0);
    __syncthreads();
    ushort* __restrict__ dst = (p == 0) ? Qf : Kf;
    const int nt0 = r0 >> 5;
    for (int i = tid; i < 2 * 9 * 64; i += 256) {
      const int ntl = i / 576;
      const int rem = i - ntl * 576;
      const int ch = rem >> 6;
      const int l2 = rem & 63;
      const s16x8 fr = *(const s16x8*)(sC + (size_t)(32 * ntl + (l2 & 31)) * CSTR +
                                       ch * 16 + (l2 >> 5) * 8);
      *(s16x8*)(dst + rf32_idx(nt0 + ntl, ch, l2)) = fr;
    }
  } else {
    // pad rows 131..159: ones at 131 (l-fusion), zeros above
    for (int i = tid; i < 29 * 64; i += 256) {
      const int e = D_ + (i >> 6);
      sT[(size_t)e * TSTR + (i & 63)] = (e == D_) ? (ushort)0x3F80 : (ushort)0;
    }
    if (eh == 0)
      epiV<0, 3>(acc, sT, sB, tg, l);
    else
      epiV<3, 2>(acc, sT, sB, tg, l);
    __syncthreads();
    const int kt0 = r0 >> 5;
    for (int i = tid; i < 2 * 2 * 5 * 64; i += 256) {
      const int ktl = i / 640;
      const int rem = i - ktl * 640;
      const int t2 = rem / 320;
      const int rem2 = rem - t2 * 320;
      const int dt = rem2 >> 6;
      const int l2 = rem2 & 63;
      const s16x8 fr = *(const s16x8*)(sT + (size_t)(32 * dt + (l2 & 31)) * TSTR +
                                       32 * ktl + 16 * t2 + 8 * (l2 >> 5));
      *(s16x8*)(Vf + vf32_idx(kt0 + ktl, t2, dt, l2)) = fr;
    }
  }
}

// ---------------------------------------------------------------------------
// Kernel 2: MFMA flash attention, 32x32, 2-tile software pipeline.
// grid(512): b=id&7 (XCD-pin), qg=id>>3 (32 queries, Q frags in LDS shared by
// 4 waves); wave w owns keys [512w,512w+512) as 16 tiles of 32.
// Per step: load V(t), prefetch K(t+2), issue QK(t+1) into the spare score
// acc (MFMA pipe), THEN softmax+PV of tile t (VALU pipe) -> the scheduler
// interleaves the independent QK MFMAs under softmax VALU. Tree-max.
// l fused via Vt ones-row (d=131); defer-max. 4-way merge at end.
// ---------------------------------------------------------------------------
__global__ __launch_bounds__(256, 2) void attn_mfma(
    const ushort* __restrict__ Qf, const ushort* __restrict__ Kf,
    const ushort* __restrict__ Vf, float* __restrict__ out) {
  const int id = blockIdx.x;
  const int b = id & 7;
  const int qg = id >> 3;
  const int tid = threadIdx.x;
  const int w = tid >> 6;
  const int l = tid & 63;
  const int l31 = l & 31;
  const int hi = l >> 5;

  __shared__ ushort sQ[9 * 64 * 8];   // 9216 B
  __shared__ float cO[4][32][COSTR];  // 68096 B
  __shared__ float cm[4][32];         // 512 B

  // stage Q fragments (one nt = contiguous 9*64*8 ushorts)
  {
    const uint4* src = (const uint4*)(Qf + rf32_idx(b * 64 + qg, 0, 0));
    uint4* dq = (uint4*)sQ;
    for (int i = tid; i < 576; i += 256) dq[i] = src[i];
  }
  // preload K tiles 0 and 1
  const int ktbase = b * 64 + w * 16;
  s16x8 kA[9], kB[9];
#pragma unroll
  for (int ch = 0; ch < 9; ++ch)
    kA[ch] = *(const s16x8*)(Kf + rf32_idx(ktbase, ch, l));
#pragma unroll
  for (int ch = 0; ch < 9; ++ch)
    kB[ch] = *(const s16x8*)(Kf + rf32_idx(ktbase + 1, ch, l));
  __syncthreads();

  f32x16 o[5];
#pragma unroll
  for (int dt = 0; dt < 5; ++dt) o[dt] = f32x16{};
  float mreg = -1e30f;

  // QK of tile 0 -> sA
  f32x16 sA = f32x16{};
#pragma unroll
  for (int ch = 0; ch < 9; ++ch) {
    const s16x8 qc = *(const s16x8*)(sQ + (ch * 64 + l) * 8);
    sA = __builtin_amdgcn_mfma_f32_32x32x16_bf16(kA[ch], qc, sA, 0, 0, 0);
  }
  f32x16 sB;

  auto softmax_pv = [&](f32x16& s, const s16x8(&vf)[2][5]) {
    // tree max (depth 4)
    float t0 = fmaxf(s[0], s[1]), t1 = fmaxf(s[2], s[3]);
    float t2_ = fmaxf(s[4], s[5]), t3 = fmaxf(s[6], s[7]);
    float t4 = fmaxf(s[8], s[9]), t5 = fmaxf(s[10], s[11]);
    float t6 = fmaxf(s[12], s[13]), t7 = fmaxf(s[14], s[15]);
    t0 = fmaxf(t0, t1);
    t2_ = fmaxf(t2_, t3);
    t4 = fmaxf(t4, t5);
    t6 = fmaxf(t6, t7);
    float tm = fmaxf(fmaxf(t0, t2_), fmaxf(t4, t6));
    tm = fmaxf(tm, __shfl_xor(tm, 32, 64));
    if (__any(tm > mreg)) {
      const float mo = mreg;
      const float mn = fmaxf(mo, tm);
      mreg = mn;
      const float f = __expf(mo - mn);
      float fr[16];
#pragma unroll
      for (int r = 0; r < 16; ++r)
        fr[r] = __shfl(f, (r & 3) + 8 * (r >> 2) + 4 * hi, 64);
#pragma unroll
      for (int dt = 0; dt < 5; ++dt)
#pragma unroll
        for (int r = 0; r < 16; ++r) o[dt][r] *= fr[r];
    }
    float pp[16];
#pragma unroll
    for (int r = 0; r < 16; ++r) pp[r] = __expf(s[r] - mreg);
    uint pk0[4], pk1[4];
#pragma unroll
    for (int wd = 0; wd < 4; ++wd) {
      pk0[wd] = bfpair(pp[2 * wd], pp[2 * wd + 1]);
      pk1[wd] = bfpair(pp[8 + 2 * wd], pp[8 + 2 * wd + 1]);
    }
    s16x8 pa[2];
    {
      const uint x0 = __shfl_xor(hi ? pk0[0] : pk0[2], 32, 64);
      const uint x1 = __shfl_xor(hi ? pk0[1] : pk0[3], 32, 64);
      uint4 u;
      u.x = hi ? x0 : pk0[0];
      u.y = hi ? x1 : pk0[1];
      u.z = hi ? pk0[2] : x0;
      u.w = hi ? pk0[3] : x1;
      pa[0] = *(s16x8*)&u;
    }
    {
      const uint x0 = __shfl_xor(hi ? pk1[0] : pk1[2], 32, 64);
      const uint x1 = __shfl_xor(hi ? pk1[1] : pk1[3], 32, 64);
      uint4 u;
      u.x = hi ? x0 : pk1[0];
      u.y = hi ? x1 : pk1[1];
      u.z = hi ? pk1[2] : x0;
      u.w = hi ? pk1[3] : x1;
      pa[1] = *(s16x8*)&u;
    }
#pragma unroll
    for (int t2 = 0; t2 < 2; ++t2)
#pragma unroll
      for (int dt = 0; dt < 5; ++dt)
        o[dt] = __builtin_amdgcn_mfma_f32_32x32x16_bf16(pa[t2], vf[t2][dt],
                                                        o[dt], 0, 0, 0);
  };

#pragma unroll
  for (int i = 0; i < 8; ++i) {
    // ---- even step: tile 2i (scores in sA); QK(2i+1) via kB; K(2i+2)->kA
    {
      s16x8 vf[2][5];
#pragma unroll
      for (int t2 = 0; t2 < 2; ++t2)
#pragma unroll
        for (int dt = 0; dt < 5; ++dt)
          vf[t2][dt] =
              *(const s16x8*)(Vf + vf32_idx(ktbase + 2 * i, t2, dt, l));
      const int tp = (2 * i + 2 < 16) ? (2 * i + 2) : 15;
#pragma unroll
      for (int ch = 0; ch < 9; ++ch)
        kA[ch] = *(const s16x8*)(Kf + rf32_idx(ktbase + tp, ch, l));
      sB = f32x16{};
#pragma unroll
      for (int ch = 0; ch < 9; ++ch) {
        const s16x8 qc = *(const s16x8*)(sQ + (ch * 64 + l) * 8);
        sB = __builtin_amdgcn_mfma_f32_32x32x16_bf16(kB[ch], qc, sB, 0, 0, 0);
      }
      softmax_pv(sA, vf);
    }
    // ---- odd step: tile 2i+1 (scores in sB); QK(2i+2) via kA; K(2i+3)->kB
    {
      s16x8 vf[2][5];
#pragma unroll
      for (int t2 = 0; t2 < 2; ++t2)
#pragma unroll
        for (int dt = 0; dt < 5; ++dt)
          vf[t2][dt] =
              *(const s16x8*)(Vf + vf32_idx(ktbase + 2 * i + 1, t2, dt, l));
      const int tp = (2 * i + 3 < 16) ? (2 * i + 3) : 15;
#pragma unroll
      for (int ch = 0; ch < 9; ++ch)
        kB[ch] = *(const s16x8*)(Kf + rf32_idx(ktbase + tp, ch, l));
      if (i < 7) {
        sA = f32x16{};
#pragma unroll
        for (int ch = 0; ch < 9; ++ch) {
          const s16x8 qc = *(const s16x8*)(sQ + (ch * 64 + l) * 8);
          sA = __builtin_amdgcn_mfma_f32_32x32x16_bf16(kA[ch], qc, sA, 0, 0, 0);
        }
      }
      softmax_pv(sB, vf);
    }
  }

  // ---- write partials and merge (symmetric, all 4 waves) ----
  if (l < 32) cm[w][l] = mreg;
#pragma unroll
  for (int dt = 0; dt < 5; ++dt) {
    const int d = 32 * dt + l31;
    if (d <= D_) {
#pragma unroll
      for (int r = 0; r < 16; ++r) {
        const int row = (r & 3) + 8 * (r >> 2) + 4 * hi;
        cO[w][row][d] = o[dt][r];
      }
    }
  }
  __syncthreads();
  for (int rr = 0; rr < 8; ++rr) {
    const int row = w * 8 + rr;
    const float m0 = cm[0][row], m1 = cm[1][row];
    const float m2 = cm[2][row], m3 = cm[3][row];
    const float M = fmaxf(fmaxf(m0, m1), fmaxf(m2, m3));
    const float e0 = __expf(m0 - M);
    const float e1 = __expf(m1 - M);
    const float e2 = __expf(m2 - M);
    const float e3 = __expf(m3 - M);
    const float lsum = cO[0][row][D_] * e0 + cO[1][row][D_] * e1 +
                       cO[2][row][D_] * e2 + cO[3][row][D_] * e3;
    const float inv = 1.f / lsum;
    float* orow = out + ((size_t)b * N_ + qg * 32 + row) * D_;
    for (int d = l; d < D_; d += 64) {
      const float val = cO[0][row][d] * e0 + cO[1][row][d] * e1 +
                        cO[2][row][d] * e2 + cO[3][row][d] * e3;
      orow[d] = val * inv;
    }
  }
}

extern "C" void kernel_launch(void* const* d_in, const int* in_sizes, int n_in,
                              void* d_out, int out_size, void* d_ws,
                              size_t ws_size, hipStream_t stream) {
  const float* q = (const float*)d_in[0];
  const float* k = (const float*)d_in[1];
  const float* v = (const float*)d_in[2];
  const float* Wq = (const float*)d_in[3];
  const float* bq = (const float*)d_in[4];
  const float* Wk = (const float*)d_in[5];
  const float* bk = (const float*)d_in[6];
  const float* Wv = (const float*)d_in[7];
  const float* bv = (const float*)d_in[8];
  float* out = (float*)d_out;

  // ws layout (bytes):
  //   Qf  [512 nt][9][64][8]u16   @ 0           (4,718,592)
  //   Kf  same                    @ 4,718,592   (4,718,592)
  //   Vf  [512 kt][2][5][64][8]   @ 9,437,184   (5,242,880)
  //   Whl [3][2][5][9][64][8]u16  @ 14,680,064  (552,960)
  char* wsb = (char*)d_ws;
  ushort* Qf = (ushort*)(wsb);
  ushort* Kf = (ushort*)(wsb + 4718592);
  ushort* Vf = (ushort*)(wsb + 9437184);
  ushort* Whl = (ushort*)(wsb + 14680064);

  hipLaunchKernelGGL(cast_w_kernel, dim3(3), dim3(256), 0, stream, Wq, Wk, Wv,
                     Whl);
  hipLaunchKernelGGL(proj_gemm, dim3(256, 3), dim3(256), 0, stream, q, k, v,
                     bq, bk, bv, Whl, Qf, Kf, Vf);
  hipLaunchKernelGGL(attn_mfma, dim3(512), dim3(256), 0, stream, Qf, Kf, Vf,
                     out);
}